// Round 1
// baseline (110.435 us; speedup 1.0000x reference)
//
#include <hip/hip_runtime.h>

// Problem: T=256 frames, 20 boxes each. Output (1, 5120, 5120) fp32
// block-diagonal: block k on the diagonal holds iou(rois[t], rois[t+1])
// with t = k+1 for k in [0,254), t = 0 for k = 255, and block 254 is zero.
// 104.9 MB of output -> pure store-bandwidth bound.

#define TT 256
#define NB 20
#define DIM (TT * NB)  // 5120

__global__ void zero_fill_kernel(float4* __restrict__ out, int n4) {
    int idx = blockIdx.x * blockDim.x + threadIdx.x;
    int stride = gridDim.x * blockDim.x;
    float4 z = make_float4(0.f, 0.f, 0.f, 0.f);
    for (int i = idx; i < n4; i += stride) {
        out[i] = z;
    }
}

__global__ void iou_blocks_kernel(const float* __restrict__ rois,
                                  float* __restrict__ out) {
    // 255 workgroups: m in [0,255). m==254 -> diagonal block 255 (iou[0]),
    // else diagonal block m (iou[m+1]). Diagonal block 254 stays zero.
    int m = blockIdx.x;
    int k = (m == 254) ? 255 : m;      // which diagonal block we write
    int t = (m == 254) ? 0 : m + 1;    // a = rois[t], b = rois[t+1]

    __shared__ float4 A[NB];
    __shared__ float4 B[NB];
    int tid = threadIdx.x;
    if (tid < NB) {
        A[tid] = ((const float4*)rois)[t * NB + tid];
        B[tid] = ((const float4*)rois)[(t + 1) * NB + tid];
    }
    __syncthreads();

    for (int e = tid; e < NB * NB; e += blockDim.x) {
        int i = e / NB;   // a index (rows)
        int j = e % NB;   // b index (cols)
        float4 a = A[i];
        float4 b = B[j];
        float ix1 = fmaxf(a.x, b.x);
        float ix2 = fminf(a.z, b.z);
        float iy1 = fmaxf(a.y, b.y);
        float iy2 = fminf(a.w, b.w);
        float inter = fmaxf(ix2 - ix1, 0.f) * fmaxf(iy2 - iy1, 0.f);
        float area_a = (a.z - a.x + 1.f) * (a.w - a.y + 1.f);
        // NOTE: reference bug preserved — b[...,2] used in BOTH factors:
        // area_b = (b.x2 - b.x1 + 1) * (b.x2 - b.y1 + 1)
        float area_b = (b.z - b.x + 1.f) * (b.z - b.y + 1.f);
        float iou = inter / (area_a + area_b - inter);
        size_t row = (size_t)(k * NB + i);
        size_t col = (size_t)(k * NB + j);
        out[row * DIM + col] = iou;
    }
}

extern "C" void kernel_launch(void* const* d_in, const int* in_sizes, int n_in,
                              void* d_out, int out_size, void* d_ws, size_t ws_size,
                              hipStream_t stream) {
    const float* rois = (const float*)d_in[0];
    float* out = (float*)d_out;

    // Zero the whole 104.9 MB output (harness poisons it to 0xAA each launch).
    int n4 = out_size / 4;  // 26,214,400 / 4 = 6,553,600 float4 stores
    zero_fill_kernel<<<2048, 256, 0, stream>>>((float4*)out, n4);

    // Fill the 255 nonzero 20x20 diagonal blocks.
    iou_blocks_kernel<<<255, 128, 0, stream>>>(rois, out);
}

// Round 2
// 106.198 us; speedup vs baseline: 1.0399x; 1.0399x over previous
//
#include <hip/hip_runtime.h>

// T=256 frames, 20 boxes. Output (1, 5120, 5120) fp32 block-diagonal:
// diagonal block d holds iou(rois[d+1], rois[d+2]) for d in [0,254),
// block 255 holds iou(rois[0], rois[1]), block 254 is zero.
// Reference bug preserved: area_b uses b[...,2] in BOTH factors.
//
// Single-pass fused kernel: one workgroup per output row. Each float4 of
// the row is either fully inside the 20-wide diagonal block (20 % 4 == 0,
// so blocks are float4-aligned) or fully zero. 104.9 MB written exactly
// once -> pure store-BW bound (~17 us at 6.3 TB/s).

#define TT 256
#define NB 20
#define DIM (TT * NB)      // 5120 floats per row
#define DIM4 (DIM / 4)     // 1280 float4 per row

__global__ void __launch_bounds__(256) fused_iou_diag_kernel(
        const float4* __restrict__ rois, float4* __restrict__ out) {
    int row = blockIdx.x;          // 0..5119
    int kr = row / NB;             // diagonal block index (wave-uniform)
    int ri = row - kr * NB;        // row within block

    bool active = (kr != 254);
    int t = (kr == 255) ? 0 : kr + 1;   // a = rois[t], b = rois[t+1]

    float4 a = make_float4(0.f, 0.f, 0.f, 0.f);
    if (active) a = rois[t * NB + ri];
    float area_a = (a.z - a.x + 1.f) * (a.w - a.y + 1.f);

    int bcol0 = kr * (NB / 4);     // first in-block float4 column
    float4* rowp = out + (size_t)row * DIM4;
    const float4* brow = rois + (t + 1) * NB;

    #pragma unroll
    for (int it = 0; it < DIM4 / 256; ++it) {
        int c4 = threadIdx.x + it * 256;
        float4 v = make_float4(0.f, 0.f, 0.f, 0.f);
        int j4 = c4 - bcol0;
        if (active && (unsigned)j4 < (unsigned)(NB / 4)) {
            float* vp = (float*)&v;
            #pragma unroll
            for (int q = 0; q < 4; ++q) {
                float4 b = brow[j4 * 4 + q];
                float ix1 = fmaxf(a.x, b.x);
                float ix2 = fminf(a.z, b.z);
                float iy1 = fmaxf(a.y, b.y);
                float iy2 = fminf(a.w, b.w);
                float inter = fmaxf(ix2 - ix1, 0.f) * fmaxf(iy2 - iy1, 0.f);
                // reference bug preserved: b.z in both factors
                float area_b = (b.z - b.x + 1.f) * (b.z - b.y + 1.f);
                vp[q] = inter / (area_a + area_b - inter);
            }
        }
        rowp[c4] = v;
    }
}

extern "C" void kernel_launch(void* const* d_in, const int* in_sizes, int n_in,
                              void* d_out, int out_size, void* d_ws, size_t ws_size,
                              hipStream_t stream) {
    const float4* rois = (const float4*)d_in[0];
    float4* out = (float4*)d_out;
    fused_iou_diag_kernel<<<DIM, 256, 0, stream>>>(rois, out);
}